// Round 4
// baseline (400.783 us; speedup 1.0000x reference)
//
#include <hip/hip_runtime.h>
#include <hip/hip_bf16.h>

// CosineSelfAttention — bf16 MFMA version, v2.
// B=4, S=4096, DM=1024, H=16, D=64. Linear attention.
//
// Pipeline:
//   msum       : msum[b] = sum_s (mask/1e4 + 1)
//   convH      : hiddenBf = bf16(hidden)
//   transposeW : Wt[n][k] bf16 for q,k,v  (B-operand wants k-contiguous)
//   gemm_qkv   : qkv[mi][m][n] bf16 = hidden @ W + bias   (128x128 MFMA tiles)
//   attnA      : per (b,h,128-row tile): mask+norm K -> KnT/VT LDS (bf16,
//                transposed) -> kv += Kn^T V via MFMA; ksum, vsum partials
//   reduceKV   : sum 32 partials per (b,h)
//   attnB      : per (b,h,64-row tile): mask+norm Q (4 threads/row),
//                ctx = Qn@kv + vsum, / (Qn.ksum + eps + msum)

#define B_  4
#define S_  4096
#define DM_ 1024
#define H_  16
#define D_  64
#define EPSF 1e-5f
#define NT_ 32   // 128-row s-tiles per (b,h) in attnA

typedef __attribute__((ext_vector_type(8))) short short8;
typedef __attribute__((ext_vector_type(4))) float f32x4;

__device__ inline unsigned short f32_to_bf16(float f) {
    unsigned int u = __builtin_bit_cast(unsigned int, f);
    u = (u + 0x7FFFu + ((u >> 16) & 1u)) >> 16;   // RNE
    return (unsigned short)u;
}
__device__ inline float bf16_to_f32(unsigned short u) {
    return __builtin_bit_cast(float, (unsigned int)u << 16);
}

__global__ __launch_bounds__(256)
void msum_kernel(const float* __restrict__ mask, float* __restrict__ msum) {
    const int b = blockIdx.x;
    float s = 0.f;
    for (int i = threadIdx.x; i < S_; i += 256)
        s += mask[b * S_ + i] / 10000.0f + 1.0f;
    for (int off = 32; off > 0; off >>= 1) s += __shfl_down(s, off);
    __shared__ float tmp[4];
    if ((threadIdx.x & 63) == 0) tmp[threadIdx.x >> 6] = s;
    __syncthreads();
    if (threadIdx.x == 0) msum[b] = tmp[0] + tmp[1] + tmp[2] + tmp[3];
}

// ---- hidden f32 -> bf16 ----------------------------------------------------
__global__ __launch_bounds__(256)
void convH(const float* __restrict__ h, unsigned short* __restrict__ hb) {
    const size_t i = ((size_t)blockIdx.x * 256 + threadIdx.x) * 8;
    const float4 a = *reinterpret_cast<const float4*>(h + i);
    const float4 c = *reinterpret_cast<const float4*>(h + i + 4);
    uint4 pk;
    pk.x = (unsigned int)f32_to_bf16(a.x) | ((unsigned int)f32_to_bf16(a.y) << 16);
    pk.y = (unsigned int)f32_to_bf16(a.z) | ((unsigned int)f32_to_bf16(a.w) << 16);
    pk.z = (unsigned int)f32_to_bf16(c.x) | ((unsigned int)f32_to_bf16(c.y) << 16);
    pk.w = (unsigned int)f32_to_bf16(c.z) | ((unsigned int)f32_to_bf16(c.w) << 16);
    *reinterpret_cast<uint4*>(hb + i) = pk;
}

// ---- Wt[n][k] = bf16(W[k][n]), per 64x64 tile ------------------------------
__global__ __launch_bounds__(256)
void transposeW(const float* __restrict__ Wq, const float* __restrict__ Wk,
                const float* __restrict__ Wv, unsigned short* __restrict__ Wt)
{
    __shared__ float T2[64 * 65];   // [nc][kr]
    const int tid = threadIdx.x;
    const int k0 = blockIdx.x * 64, n0 = blockIdx.y * 64, mi = blockIdx.z;
    const float* W = (mi == 0) ? Wq : (mi == 1) ? Wk : Wv;

#pragma unroll
    for (int t = 0; t < 4; ++t) {
        const int idx = t * 256 + tid;
        const int kr = idx >> 4, nc4 = idx & 15;
        const float4 v = *reinterpret_cast<const float4*>(
            &W[(size_t)(k0 + kr) * DM_ + n0 + nc4 * 4]);
        T2[(nc4 * 4 + 0) * 65 + kr] = v.x;
        T2[(nc4 * 4 + 1) * 65 + kr] = v.y;
        T2[(nc4 * 4 + 2) * 65 + kr] = v.z;
        T2[(nc4 * 4 + 3) * 65 + kr] = v.w;
    }
    __syncthreads();
#pragma unroll
    for (int t = 0; t < 4; ++t) {
        const int idx = t * 256 + tid;
        const int nr = idx >> 4, kc4 = idx & 15;
        unsigned int p0 = (unsigned int)f32_to_bf16(T2[nr * 65 + kc4 * 4 + 0]) |
                          ((unsigned int)f32_to_bf16(T2[nr * 65 + kc4 * 4 + 1]) << 16);
        unsigned int p1 = (unsigned int)f32_to_bf16(T2[nr * 65 + kc4 * 4 + 2]) |
                          ((unsigned int)f32_to_bf16(T2[nr * 65 + kc4 * 4 + 3]) << 16);
        uint2 pk; pk.x = p0; pk.y = p1;
        *reinterpret_cast<uint2*>(
            &Wt[(size_t)mi * DM_ * DM_ + (size_t)(n0 + nr) * DM_ + k0 + kc4 * 4]) = pk;
    }
}

// ---- qkv = bf16(hidden @ W + bias), 128x128 tile, 4 waves ------------------
__global__ __launch_bounds__(256)
void gemm_qkv(const unsigned short* __restrict__ hb, const unsigned short* __restrict__ Wt,
              const float* __restrict__ bq, const float* __restrict__ bk,
              const float* __restrict__ bv, unsigned short* __restrict__ qkv)
{
    __shared__ unsigned short As[128 * 40];  // [m][k], stride 40
    __shared__ unsigned short Bs[128 * 40];  // [n][k]

    const int tid = threadIdx.x;
    const int lane = tid & 63, w = tid >> 6;
    const int lx = lane & 15, gk = lane >> 4;
    const int wr = w >> 1, wc = w & 1;
    const int nbase = blockIdx.x * 128, mbase = blockIdx.y * 128, mi = blockIdx.z;
    const float* bias = (mi == 0) ? bq : (mi == 1) ? bk : bv;
    const unsigned short* Wm = Wt + (size_t)mi * DM_ * DM_;
    unsigned short* outm = qkv + (size_t)mi * (B_ * S_) * DM_;

    f32x4 acc[4][4] = {};

    for (int kt = 0; kt < DM_ / 32; ++kt) {
#pragma unroll
        for (int t = 0; t < 2; ++t) {
            const int i = t * 256 + tid;
            const int r = i >> 2, g = i & 3;
            *reinterpret_cast<short8*>(&As[r * 40 + g * 8]) =
                *reinterpret_cast<const short8*>(
                    &hb[(size_t)(mbase + r) * DM_ + kt * 32 + g * 8]);
            *reinterpret_cast<short8*>(&Bs[r * 40 + g * 8]) =
                *reinterpret_cast<const short8*>(
                    &Wm[(size_t)(nbase + r) * DM_ + kt * 32 + g * 8]);
        }
        __syncthreads();
        short8 a[4], bb[4];
#pragma unroll
        for (int f = 0; f < 4; ++f)
            a[f] = *reinterpret_cast<const short8*>(&As[(wr * 64 + f * 16 + lx) * 40 + gk * 8]);
#pragma unroll
        for (int n = 0; n < 4; ++n)
            bb[n] = *reinterpret_cast<const short8*>(&Bs[(wc * 64 + n * 16 + lx) * 40 + gk * 8]);
#pragma unroll
        for (int f = 0; f < 4; ++f)
#pragma unroll
            for (int n = 0; n < 4; ++n)
                acc[f][n] = __builtin_amdgcn_mfma_f32_16x16x32_bf16(a[f], bb[n], acc[f][n], 0, 0, 0);
        __syncthreads();
    }

#pragma unroll
    for (int n = 0; n < 4; ++n) {
        const int col = nbase + wc * 64 + n * 16 + lx;
        const float bcol = bias[col];
#pragma unroll
        for (int f = 0; f < 4; ++f) {
            const int rbase = mbase + wr * 64 + f * 16 + gk * 4;
#pragma unroll
            for (int reg = 0; reg < 4; ++reg)
                outm[(size_t)(rbase + reg) * DM_ + col] = f32_to_bf16(acc[f][n][reg] + bcol);
        }
    }
}

// ---- attnA: per (b,h,128-row tile): norm K, kv += Kn^T V, ksum, vsum -------
__global__ __launch_bounds__(256)
void attnA(const unsigned short* __restrict__ qkv, const float* __restrict__ mask,
           float* __restrict__ kvpart, float* __restrict__ kspart,
           float* __restrict__ vspart)
{
    __shared__ unsigned short KnT[64 * 136];  // [d][r], stride 136
    __shared__ unsigned short VT[64 * 136];   // [e][r]

    const int tid = threadIdx.x;
    const int lane = tid & 63, w = tid >> 6;
    const int lx = lane & 15, gk = lane >> 4;
    const int stile = blockIdx.x, h = blockIdx.y, b = blockIdx.z;
    const int col0 = h * D_;
    const int s0 = stile * 128;
    const int bh = b * H_ + h;

    const int rr = tid & 127;      // row within tile
    const int isV = tid >> 7;      // waves 0-1: K rows, waves 2-3: V rows
    const int srow = s0 + rr;

    const unsigned short* grow = qkv + (size_t)(1 + isV) * (B_ * S_) * DM_ +
                                 (size_t)(b * S_ + srow) * DM_ + col0;

    if (!isV) {
        // K row: load, mask, normalize, write transposed bf16
        const float m = mask[b * S_ + srow] / 10000.0f + 1.0f;
        short8 kr8[8];
#pragma unroll
        for (int v = 0; v < 8; ++v)
            kr8[v] = *reinterpret_cast<const short8*>(grow + v * 8);
        float x[64];
        float ss = 0.f;
#pragma unroll
        for (int v = 0; v < 8; ++v)
#pragma unroll
            for (int j = 0; j < 8; ++j) {
                const float f = bf16_to_f32((unsigned short)kr8[v][j]) * m;
                x[v * 8 + j] = f;
                ss += f * f;
            }
        const float inv = 1.0f / (sqrtf(ss) + EPSF);
#pragma unroll
        for (int d = 0; d < 64; ++d)
            KnT[d * 136 + rr] = f32_to_bf16(x[d] * inv);
    } else {
        // V row: load, write transposed (no mask)
        short8 vr8[8];
#pragma unroll
        for (int v = 0; v < 8; ++v)
            vr8[v] = *reinterpret_cast<const short8*>(grow + v * 8);
#pragma unroll
        for (int v = 0; v < 8; ++v)
#pragma unroll
            for (int j = 0; j < 8; ++j)
                VT[(v * 8 + j) * 136 + rr] = (unsigned short)vr8[v][j];
    }
    __syncthreads();

    // kv MFMA: D[dd][e] = sum_r KnT[dd][r] * VT[e][r]; wave w: dd in [w*16, +16)
    f32x4 kvacc[4] = {};
#pragma unroll
    for (int kk = 0; kk < 4; ++kk) {
        const short8 af = *reinterpret_cast<const short8*>(
            &KnT[(w * 16 + lx) * 136 + kk * 32 + gk * 8]);
#pragma unroll
        for (int nb = 0; nb < 4; ++nb) {
            const short8 bf = *reinterpret_cast<const short8*>(
                &VT[(nb * 16 + lx) * 136 + kk * 32 + gk * 8]);
            kvacc[nb] = __builtin_amdgcn_mfma_f32_16x16x32_bf16(af, bf, kvacc[nb], 0, 0, 0);
        }
    }

    float* kvp = kvpart + (size_t)(bh * NT_ + stile) * D_ * D_;
#pragma unroll
    for (int nb = 0; nb < 4; ++nb) {
        const int e = nb * 16 + lx;
#pragma unroll
        for (int reg = 0; reg < 4; ++reg) {
            const int dd = w * 16 + gk * 4 + reg;
            kvp[dd * D_ + e] = kvacc[nb][reg];
        }
    }

    // ksum (threads 0..63) / vsum (threads 64..127) over this tile's 128 rows
    if (tid < 64) {
        float s = 0.f;
#pragma unroll
        for (int r8 = 0; r8 < 16; ++r8) {
            const short8 v = *reinterpret_cast<const short8*>(&KnT[tid * 136 + r8 * 8]);
#pragma unroll
            for (int j = 0; j < 8; ++j) s += bf16_to_f32((unsigned short)v[j]);
        }
        kspart[(bh * NT_ + stile) * D_ + tid] = s;
    } else if (tid < 128) {
        const int e = tid - 64;
        float s = 0.f;
#pragma unroll
        for (int r8 = 0; r8 < 16; ++r8) {
            const short8 v = *reinterpret_cast<const short8*>(&VT[e * 136 + r8 * 8]);
#pragma unroll
            for (int j = 0; j < 8; ++j) s += bf16_to_f32((unsigned short)v[j]);
        }
        vspart[(bh * NT_ + stile) * D_ + e] = s;
    }
}

__global__ __launch_bounds__(256)
void reduceKV(const float* __restrict__ kvpart, const float* __restrict__ kspart,
              const float* __restrict__ vspart, float* __restrict__ kv,
              float* __restrict__ ksum, float* __restrict__ vsum)
{
    const int bh = blockIdx.x;
    for (int idx = threadIdx.x; idx < D_ * D_; idx += 256) {
        float s = 0.f;
        for (int t = 0; t < NT_; ++t)
            s += kvpart[(size_t)(bh * NT_ + t) * D_ * D_ + idx];
        kv[(size_t)bh * D_ * D_ + idx] = s;
    }
    if (threadIdx.x < D_) {
        float sk = 0.f, sv = 0.f;
        for (int t = 0; t < NT_; ++t) {
            sk += kspart[(bh * NT_ + t) * D_ + threadIdx.x];
            sv += vspart[(bh * NT_ + t) * D_ + threadIdx.x];
        }
        ksum[bh * D_ + threadIdx.x] = sk;
        vsum[bh * D_ + threadIdx.x] = sv;
    }
}

// ---- attnB: per (b,h,64-row tile), 4 threads/row ---------------------------
__global__ __launch_bounds__(256)
void attnB(const unsigned short* __restrict__ qkv, const float* __restrict__ mask,
           const float* __restrict__ kv, const float* __restrict__ ksum,
           const float* __restrict__ vsum, const float* __restrict__ msum,
           float* __restrict__ out)
{
    __shared__ unsigned short Qs[64 * 72];  // [r][d], stride 72
    __shared__ float KVs[64 * 64];          // [d][e]
    __shared__ float ksum_s[64], vsum_s[64];

    const int tid = threadIdx.x;
    const int stile = blockIdx.x, h = blockIdx.y, b = blockIdx.z;
    const int col0 = h * D_;
    const int s0 = stile * 64;
    const int bh = b * H_ + h;

#pragma unroll
    for (int t = 0; t < 2; ++t) {
        const int i = t * 256 + tid;
        const int r = i >> 3, c8 = i & 7;
        *reinterpret_cast<short8*>(&Qs[r * 72 + c8 * 8]) =
            *reinterpret_cast<const short8*>(
                &qkv[(size_t)(b * S_ + s0 + r) * DM_ + col0 + c8 * 8]);
    }
    {
        const float4* src = reinterpret_cast<const float4*>(kv + (size_t)bh * D_ * D_);
        float4* dst = reinterpret_cast<float4*>(&KVs[0]);
#pragma unroll
        for (int t = 0; t < 4; ++t) dst[t * 256 + tid] = src[t * 256 + tid];
        if (tid < 64) ksum_s[tid] = ksum[bh * D_ + tid];
        else if (tid < 128) vsum_s[tid - 64] = vsum[bh * D_ + (tid - 64)];
    }
    __syncthreads();

    const int r = tid >> 2, q = tid & 3;        // row, e-quarter
    const int srow = s0 + r;
    const float m = mask[b * S_ + srow] / 10000.0f + 1.0f;
    const float msumb = msum[b];

    float x[64];
    float ss = 0.f;
#pragma unroll
    for (int v = 0; v < 8; ++v) {
        const short8 rv = *reinterpret_cast<const short8*>(&Qs[r * 72 + v * 8]);
#pragma unroll
        for (int j = 0; j < 8; ++j) {
            const float f = bf16_to_f32((unsigned short)rv[j]) * m;
            x[v * 8 + j] = f;
            ss += f * f;
        }
    }
    const float inv = 1.0f / (sqrtf(ss) + EPSF);

    float acc[16] = {};
    float nrm = 0.f;
    const int e0 = q * 16;
#pragma unroll
    for (int d = 0; d < 64; ++d) {
        const float qd = x[d] * inv;
        nrm += qd * ksum_s[d];
#pragma unroll
        for (int c4 = 0; c4 < 4; ++c4) {
            const float4 kv4 = *reinterpret_cast<const float4*>(&KVs[d * 64 + e0 + c4 * 4]);
            acc[c4 * 4 + 0] += qd * kv4.x;
            acc[c4 * 4 + 1] += qd * kv4.y;
            acc[c4 * 4 + 2] += qd * kv4.z;
            acc[c4 * 4 + 3] += qd * kv4.w;
        }
    }

    const float denom = nrm + EPSF + msumb;
    const float dinv = 1.0f / denom;
#pragma unroll
    for (int c4 = 0; c4 < 4; ++c4) {
        float4 o;
        o.x = (acc[c4 * 4 + 0] + vsum_s[e0 + c4 * 4 + 0]) * dinv;
        o.y = (acc[c4 * 4 + 1] + vsum_s[e0 + c4 * 4 + 1]) * dinv;
        o.z = (acc[c4 * 4 + 2] + vsum_s[e0 + c4 * 4 + 2]) * dinv;
        o.w = (acc[c4 * 4 + 3] + vsum_s[e0 + c4 * 4 + 3]) * dinv;
        *reinterpret_cast<float4*>(
            &out[(size_t)(b * S_ + srow) * DM_ + col0 + e0 + c4 * 4]) = o;
    }
}

extern "C" void kernel_launch(void* const* d_in, const int* in_sizes, int n_in,
                              void* d_out, int out_size, void* d_ws, size_t ws_size,
                              hipStream_t stream) {
    const float* hidden = (const float*)d_in[0];
    const float* mask   = (const float*)d_in[1];
    const float* Wq     = (const float*)d_in[2];
    const float* bq     = (const float*)d_in[3];
    const float* Wk     = (const float*)d_in[4];
    const float* bk     = (const float*)d_in[5];
    const float* Wv     = (const float*)d_in[6];
    const float* bv     = (const float*)d_in[7];
    float* out = (float*)d_out;

    // workspace layout (~168 MB)
    unsigned short* hb  = (unsigned short*)d_ws;                  // 16M shorts
    unsigned short* Wt  = hb + (size_t)B_ * S_ * DM_;             // 3M shorts
    unsigned short* qkv = Wt + (size_t)3 * DM_ * DM_;             // 48M shorts
    float* kvpart = (float*)(qkv + (size_t)3 * (B_ * S_) * DM_);  // B*H*NT*D*D
    float* kspart = kvpart + (size_t)B_ * H_ * NT_ * D_ * D_;
    float* vspart = kspart + (size_t)B_ * H_ * NT_ * D_;
    float* kvf    = vspart + (size_t)B_ * H_ * NT_ * D_;
    float* ksum   = kvf + (size_t)B_ * H_ * D_ * D_;
    float* vsum   = ksum + (size_t)B_ * H_ * D_;
    float* msum   = vsum + (size_t)B_ * H_ * D_;

    msum_kernel<<<B_, 256, 0, stream>>>(mask, msum);
    convH<<<(B_ * S_ * DM_) / (256 * 8), 256, 0, stream>>>(hidden, hb);
    transposeW<<<dim3(16, 16, 3), 256, 0, stream>>>(Wq, Wk, Wv, Wt);
    gemm_qkv<<<dim3(8, 128, 3), 256, 0, stream>>>(hb, Wt, bq, bk, bv, qkv);
    attnA<<<dim3(NT_, H_, B_), 256, 0, stream>>>(qkv, mask, kvpart, kspart, vspart);
    reduceKV<<<B_ * H_, 256, 0, stream>>>(kvpart, kspart, vspart, kvf, ksum, vsum);
    attnB<<<dim3(S_ / 64, H_, B_), 256, 0, stream>>>(qkv, mask, kvf, ksum, vsum, msum, out);
}

// Round 7
// 346.885 us; speedup vs baseline: 1.1554x; 1.1554x over previous
//
#include <hip/hip_runtime.h>
#include <hip/hip_bf16.h>

// CosineSelfAttention — bf16 MFMA version, v3.
// B=4, S=4096, DM=1024, H=16, D=64. Linear attention.
//
// v3 changes (gemm_qkv only):
//   * global_load_lds (16B) staging, BK=64, single LDS buffer
//   * T2 XOR swizzle both-sides: pre-swizzled global source + swizzled ds_read
//     (slot ^= row&7 at 16B granularity) -> 2-way (free) LDS reads
//   * T1 bijective XCD swizzle of the 3072-block grid (384 blocks/XCD)

#define B_  4
#define S_  4096
#define DM_ 1024
#define H_  16
#define D_  64
#define EPSF 1e-5f
#define NT_ 32   // 128-row s-tiles per (b,h) in attnA
#define BKG 64   // gemm k-step

typedef __attribute__((ext_vector_type(8))) short short8;
typedef __attribute__((ext_vector_type(4))) float f32x4;

__device__ inline unsigned short f32_to_bf16(float f) {
    unsigned int u = __builtin_bit_cast(unsigned int, f);
    u = (u + 0x7FFFu + ((u >> 16) & 1u)) >> 16;   // RNE
    return (unsigned short)u;
}
__device__ inline float bf16_to_f32(unsigned short u) {
    return __builtin_bit_cast(float, (unsigned int)u << 16);
}

__global__ __launch_bounds__(256)
void msum_kernel(const float* __restrict__ mask, float* __restrict__ msum) {
    const int b = blockIdx.x;
    float s = 0.f;
    for (int i = threadIdx.x; i < S_; i += 256)
        s += mask[b * S_ + i] / 10000.0f + 1.0f;
    for (int off = 32; off > 0; off >>= 1) s += __shfl_down(s, off);
    __shared__ float tmp[4];
    if ((threadIdx.x & 63) == 0) tmp[threadIdx.x >> 6] = s;
    __syncthreads();
    if (threadIdx.x == 0) msum[b] = tmp[0] + tmp[1] + tmp[2] + tmp[3];
}

// ---- hidden f32 -> bf16 ----------------------------------------------------
__global__ __launch_bounds__(256)
void convH(const float* __restrict__ h, unsigned short* __restrict__ hb) {
    const size_t i = ((size_t)blockIdx.x * 256 + threadIdx.x) * 8;
    const float4 a = *reinterpret_cast<const float4*>(h + i);
    const float4 c = *reinterpret_cast<const float4*>(h + i + 4);
    uint4 pk;
    pk.x = (unsigned int)f32_to_bf16(a.x) | ((unsigned int)f32_to_bf16(a.y) << 16);
    pk.y = (unsigned int)f32_to_bf16(a.z) | ((unsigned int)f32_to_bf16(a.w) << 16);
    pk.z = (unsigned int)f32_to_bf16(c.x) | ((unsigned int)f32_to_bf16(c.y) << 16);
    pk.w = (unsigned int)f32_to_bf16(c.z) | ((unsigned int)f32_to_bf16(c.w) << 16);
    *reinterpret_cast<uint4*>(hb + i) = pk;
}

// ---- Wt[n][k] = bf16(W[k][n]), per 64x64 tile ------------------------------
__global__ __launch_bounds__(256)
void transposeW(const float* __restrict__ Wq, const float* __restrict__ Wk,
                const float* __restrict__ Wv, unsigned short* __restrict__ Wt)
{
    __shared__ float T2[64 * 65];   // [nc][kr]
    const int tid = threadIdx.x;
    const int k0 = blockIdx.x * 64, n0 = blockIdx.y * 64, mi = blockIdx.z;
    const float* W = (mi == 0) ? Wq : (mi == 1) ? Wk : Wv;

#pragma unroll
    for (int t = 0; t < 4; ++t) {
        const int idx = t * 256 + tid;
        const int kr = idx >> 4, nc4 = idx & 15;
        const float4 v = *reinterpret_cast<const float4*>(
            &W[(size_t)(k0 + kr) * DM_ + n0 + nc4 * 4]);
        T2[(nc4 * 4 + 0) * 65 + kr] = v.x;
        T2[(nc4 * 4 + 1) * 65 + kr] = v.y;
        T2[(nc4 * 4 + 2) * 65 + kr] = v.z;
        T2[(nc4 * 4 + 3) * 65 + kr] = v.w;
    }
    __syncthreads();
#pragma unroll
    for (int t = 0; t < 4; ++t) {
        const int idx = t * 256 + tid;
        const int nr = idx >> 4, kc4 = idx & 15;
        unsigned int p0 = (unsigned int)f32_to_bf16(T2[nr * 65 + kc4 * 4 + 0]) |
                          ((unsigned int)f32_to_bf16(T2[nr * 65 + kc4 * 4 + 1]) << 16);
        unsigned int p1 = (unsigned int)f32_to_bf16(T2[nr * 65 + kc4 * 4 + 2]) |
                          ((unsigned int)f32_to_bf16(T2[nr * 65 + kc4 * 4 + 3]) << 16);
        uint2 pk; pk.x = p0; pk.y = p1;
        *reinterpret_cast<uint2*>(
            &Wt[(size_t)mi * DM_ * DM_ + (size_t)(n0 + nr) * DM_ + k0 + kc4 * 4]) = pk;
    }
}

// ---- qkv = bf16(hidden @ W + bias), 128x128 tile, 4 waves, glds+swizzle ----
__global__ __launch_bounds__(256)
void gemm_qkv(const unsigned short* __restrict__ hb, const unsigned short* __restrict__ Wt,
              const float* __restrict__ bq, const float* __restrict__ bk,
              const float* __restrict__ bv, unsigned short* __restrict__ qkv)
{
    // linear LDS (global_load_lds needs contiguous dest); XOR swizzle at 16B
    // slot granularity: phys_slot = log_slot ^ (row & 7). 128 rows x 128 B.
    __shared__ __align__(16) unsigned short As[128 * BKG];
    __shared__ __align__(16) unsigned short Bs[128 * BKG];

    const int tid = threadIdx.x;
    const int lane = tid & 63, w = tid >> 6;
    const int lx = lane & 15, gk = lane >> 4;
    const int wr = w >> 1, wc = w & 1;

    // T1: bijective XCD swizzle. 3072 blocks, 8 XCDs -> 384 contiguous ids each.
    const int wg = blockIdx.x;
    const int swz = (wg & 7) * 384 + (wg >> 3);
    const int mi = swz >> 10;            // 0..2
    const int rem = swz & 1023;
    const int mbase = (rem >> 3) * 128;  // 128 m-tiles
    const int nbase = (rem & 7) * 128;   // 8 n-tiles

    const float* bias = (mi == 0) ? bq : (mi == 1) ? bk : bv;
    const unsigned short* Wm = Wt + (size_t)mi * DM_ * DM_;
    unsigned short* outm = qkv + (size_t)mi * (B_ * S_) * DM_;

    // staging: wave w covers rows [w*32, w*32+32); instr t covers 8 rows.
    // lane L -> LDS (row = base8 + (L>>3), phys slot = L&7). Since base8 % 8 == 0,
    // row&7 = L>>3, so logical slot = (L&7) ^ (L>>3). Source is per-lane global.
    const int srow = w * 32 + (lane >> 3);
    const int sslot = (lane & 7) ^ (lane >> 3);
    const unsigned short* aSrc = hb + (size_t)(mbase + srow) * DM_ + sslot * 8;
    const unsigned short* bSrc = Wm + (size_t)(nbase + srow) * DM_ + sslot * 8;

    f32x4 acc[4][4] = {};

    for (int kt = 0; kt < DM_ / BKG; ++kt) {
#pragma unroll
        for (int t = 0; t < 4; ++t) {
            __builtin_amdgcn_global_load_lds(
                (const __attribute__((address_space(1))) unsigned int*)(aSrc + kt * BKG + (size_t)t * 8 * DM_),
                (__attribute__((address_space(3))) unsigned int*)&As[(w * 32 + t * 8) * BKG],
                16, 0, 0);
            __builtin_amdgcn_global_load_lds(
                (const __attribute__((address_space(1))) unsigned int*)(bSrc + kt * BKG + (size_t)t * 8 * DM_),
                (__attribute__((address_space(3))) unsigned int*)&Bs[(w * 32 + t * 8) * BKG],
                16, 0, 0);
        }
        __syncthreads();   // drains vmcnt (compiler-inserted) — data ready

#pragma unroll
        for (int ks = 0; ks < 2; ++ks) {
            short8 a[4], bb[4];
#pragma unroll
            for (int f = 0; f < 4; ++f) {
                const int row = wr * 64 + f * 16 + lx;   // row&7 == lx&7
                a[f] = *reinterpret_cast<const short8*>(
                    &As[row * BKG + (((ks * 4 + gk) ^ (lx & 7)) * 8)]);
            }
#pragma unroll
            for (int n = 0; n < 4; ++n) {
                const int row = wc * 64 + n * 16 + lx;
                bb[n] = *reinterpret_cast<const short8*>(
                    &Bs[row * BKG + (((ks * 4 + gk) ^ (lx & 7)) * 8)]);
            }
#pragma unroll
            for (int f = 0; f < 4; ++f)
#pragma unroll
                for (int n = 0; n < 4; ++n)
                    acc[f][n] = __builtin_amdgcn_mfma_f32_16x16x32_bf16(a[f], bb[n], acc[f][n], 0, 0, 0);
        }
        __syncthreads();
    }

    // epilogue: + bias, -> bf16
#pragma unroll
    for (int n = 0; n < 4; ++n) {
        const int col = nbase + wc * 64 + n * 16 + lx;
        const float bcol = bias[col];
#pragma unroll
        for (int f = 0; f < 4; ++f) {
            const int rbase = mbase + wr * 64 + f * 16 + gk * 4;
#pragma unroll
            for (int reg = 0; reg < 4; ++reg)
                outm[(size_t)(rbase + reg) * DM_ + col] = f32_to_bf16(acc[f][n][reg] + bcol);
        }
    }
}

// ---- attnA: per (b,h,128-row tile): norm K, kv += Kn^T V, ksum, vsum -------
__global__ __launch_bounds__(256)
void attnA(const unsigned short* __restrict__ qkv, const float* __restrict__ mask,
           float* __restrict__ kvpart, float* __restrict__ kspart,
           float* __restrict__ vspart)
{
    __shared__ unsigned short KnT[64 * 136];  // [d][r], stride 136
    __shared__ unsigned short VT[64 * 136];   // [e][r]

    const int tid = threadIdx.x;
    const int lane = tid & 63, w = tid >> 6;
    const int lx = lane & 15, gk = lane >> 4;
    const int stile = blockIdx.x, h = blockIdx.y, b = blockIdx.z;
    const int col0 = h * D_;
    const int s0 = stile * 128;
    const int bh = b * H_ + h;

    const int rr = tid & 127;      // row within tile
    const int isV = tid >> 7;      // waves 0-1: K rows, waves 2-3: V rows
    const int srow = s0 + rr;

    const unsigned short* grow = qkv + (size_t)(1 + isV) * (B_ * S_) * DM_ +
                                 (size_t)(b * S_ + srow) * DM_ + col0;

    if (!isV) {
        const float m = mask[b * S_ + srow] / 10000.0f + 1.0f;
        short8 kr8[8];
#pragma unroll
        for (int v = 0; v < 8; ++v)
            kr8[v] = *reinterpret_cast<const short8*>(grow + v * 8);
        float x[64];
        float ss = 0.f;
#pragma unroll
        for (int v = 0; v < 8; ++v)
#pragma unroll
            for (int j = 0; j < 8; ++j) {
                const float f = bf16_to_f32((unsigned short)kr8[v][j]) * m;
                x[v * 8 + j] = f;
                ss += f * f;
            }
        const float inv = 1.0f / (sqrtf(ss) + EPSF);
#pragma unroll
        for (int d = 0; d < 64; ++d)
            KnT[d * 136 + rr] = f32_to_bf16(x[d] * inv);
    } else {
        short8 vr8[8];
#pragma unroll
        for (int v = 0; v < 8; ++v)
            vr8[v] = *reinterpret_cast<const short8*>(grow + v * 8);
#pragma unroll
        for (int v = 0; v < 8; ++v)
#pragma unroll
            for (int j = 0; j < 8; ++j)
                VT[(v * 8 + j) * 136 + rr] = (unsigned short)vr8[v][j];
    }
    __syncthreads();

    f32x4 kvacc[4] = {};
#pragma unroll
    for (int kk = 0; kk < 4; ++kk) {
        const short8 af = *reinterpret_cast<const short8*>(
            &KnT[(w * 16 + lx) * 136 + kk * 32 + gk * 8]);
#pragma unroll
        for (int nb = 0; nb < 4; ++nb) {
            const short8 bf = *reinterpret_cast<const short8*>(
                &VT[(nb * 16 + lx) * 136 + kk * 32 + gk * 8]);
            kvacc[nb] = __builtin_amdgcn_mfma_f32_16x16x32_bf16(af, bf, kvacc[nb], 0, 0, 0);
        }
    }

    float* kvp = kvpart + (size_t)(bh * NT_ + stile) * D_ * D_;
#pragma unroll
    for (int nb = 0; nb < 4; ++nb) {
        const int e = nb * 16 + lx;
#pragma unroll
        for (int reg = 0; reg < 4; ++reg) {
            const int dd = w * 16 + gk * 4 + reg;
            kvp[dd * D_ + e] = kvacc[nb][reg];
        }
    }

    if (tid < 64) {
        float s = 0.f;
#pragma unroll
        for (int r8 = 0; r8 < 16; ++r8) {
            const short8 v = *reinterpret_cast<const short8*>(&KnT[tid * 136 + r8 * 8]);
#pragma unroll
            for (int j = 0; j < 8; ++j) s += bf16_to_f32((unsigned short)v[j]);
        }
        kspart[(bh * NT_ + stile) * D_ + tid] = s;
    } else if (tid < 128) {
        const int e = tid - 64;
        float s = 0.f;
#pragma unroll
        for (int r8 = 0; r8 < 16; ++r8) {
            const short8 v = *reinterpret_cast<const short8*>(&VT[e * 136 + r8 * 8]);
#pragma unroll
            for (int j = 0; j < 8; ++j) s += bf16_to_f32((unsigned short)v[j]);
        }
        vspart[(bh * NT_ + stile) * D_ + e] = s;
    }
}

__global__ __launch_bounds__(256)
void reduceKV(const float* __restrict__ kvpart, const float* __restrict__ kspart,
              const float* __restrict__ vspart, float* __restrict__ kv,
              float* __restrict__ ksum, float* __restrict__ vsum)
{
    const int bh = blockIdx.x;
    for (int idx = threadIdx.x; idx < D_ * D_; idx += 256) {
        float s = 0.f;
        for (int t = 0; t < NT_; ++t)
            s += kvpart[(size_t)(bh * NT_ + t) * D_ * D_ + idx];
        kv[(size_t)bh * D_ * D_ + idx] = s;
    }
    if (threadIdx.x < D_) {
        float sk = 0.f, sv = 0.f;
        for (int t = 0; t < NT_; ++t) {
            sk += kspart[(bh * NT_ + t) * D_ + threadIdx.x];
            sv += vspart[(bh * NT_ + t) * D_ + threadIdx.x];
        }
        ksum[bh * D_ + threadIdx.x] = sk;
        vsum[bh * D_ + threadIdx.x] = sv;
    }
}

// ---- attnB: per (b,h,64-row tile), 4 threads/row ---------------------------
__global__ __launch_bounds__(256)
void attnB(const unsigned short* __restrict__ qkv, const float* __restrict__ mask,
           const float* __restrict__ kv, const float* __restrict__ ksum,
           const float* __restrict__ vsum, const float* __restrict__ msum,
           float* __restrict__ out)
{
    __shared__ unsigned short Qs[64 * 72];  // [r][d], stride 72
    __shared__ float KVs[64 * 64];          // [d][e]
    __shared__ float ksum_s[64], vsum_s[64];

    const int tid = threadIdx.x;
    const int stile = blockIdx.x, h = blockIdx.y, b = blockIdx.z;
    const int col0 = h * D_;
    const int s0 = stile * 64;
    const int bh = b * H_ + h;

#pragma unroll
    for (int t = 0; t < 2; ++t) {
        const int i = t * 256 + tid;
        const int r = i >> 3, c8 = i & 7;
        *reinterpret_cast<short8*>(&Qs[r * 72 + c8 * 8]) =
            *reinterpret_cast<const short8*>(
                &qkv[(size_t)(b * S_ + s0 + r) * DM_ + col0 + c8 * 8]);
    }
    {
        const float4* src = reinterpret_cast<const float4*>(kv + (size_t)bh * D_ * D_);
        float4* dst = reinterpret_cast<float4*>(&KVs[0]);
#pragma unroll
        for (int t = 0; t < 4; ++t) dst[t * 256 + tid] = src[t * 256 + tid];
        if (tid < 64) ksum_s[tid] = ksum[bh * D_ + tid];
        else if (tid < 128) vsum_s[tid - 64] = vsum[bh * D_ + (tid - 64)];
    }
    __syncthreads();

    const int r = tid >> 2, q = tid & 3;
    const int srow = s0 + r;
    const float m = mask[b * S_ + srow] / 10000.0f + 1.0f;
    const float msumb = msum[b];

    float x[64];
    float ss = 0.f;
#pragma unroll
    for (int v = 0; v < 8; ++v) {
        const short8 rv = *reinterpret_cast<const short8*>(&Qs[r * 72 + v * 8]);
#pragma unroll
        for (int j = 0; j < 8; ++j) {
            const float f = bf16_to_f32((unsigned short)rv[j]) * m;
            x[v * 8 + j] = f;
            ss += f * f;
        }
    }
    const float inv = 1.0f / (sqrtf(ss) + EPSF);

    float acc[16] = {};
    float nrm = 0.f;
    const int e0 = q * 16;
#pragma unroll
    for (int d = 0; d < 64; ++d) {
        const float qd = x[d] * inv;
        nrm += qd * ksum_s[d];
#pragma unroll
        for (int c4 = 0; c4 < 4; ++c4) {
            const float4 kv4 = *reinterpret_cast<const float4*>(&KVs[d * 64 + e0 + c4 * 4]);
            acc[c4 * 4 + 0] += qd * kv4.x;
            acc[c4 * 4 + 1] += qd * kv4.y;
            acc[c4 * 4 + 2] += qd * kv4.z;
            acc[c4 * 4 + 3] += qd * kv4.w;
        }
    }

    const float denom = nrm + EPSF + msumb;
    const float dinv = 1.0f / denom;
#pragma unroll
    for (int c4 = 0; c4 < 4; ++c4) {
        float4 o;
        o.x = (acc[c4 * 4 + 0] + vsum_s[e0 + c4 * 4 + 0]) * dinv;
        o.y = (acc[c4 * 4 + 1] + vsum_s[e0 + c4 * 4 + 1]) * dinv;
        o.z = (acc[c4 * 4 + 2] + vsum_s[e0 + c4 * 4 + 2]) * dinv;
        o.w = (acc[c4 * 4 + 3] + vsum_s[e0 + c4 * 4 + 3]) * dinv;
        *reinterpret_cast<float4*>(
            &out[(size_t)(b * S_ + srow) * DM_ + col0 + e0 + c4 * 4]) = o;
    }
}

extern "C" void kernel_launch(void* const* d_in, const int* in_sizes, int n_in,
                              void* d_out, int out_size, void* d_ws, size_t ws_size,
                              hipStream_t stream) {
    const float* hidden = (const float*)d_in[0];
    const float* mask   = (const float*)d_in[1];
    const float* Wq     = (const float*)d_in[2];
    const float* bq     = (const float*)d_in[3];
    const float* Wk     = (const float*)d_in[4];
    const float* bk     = (const float*)d_in[5];
    const float* Wv     = (const float*)d_in[6];
    const float* bv     = (const float*)d_in[7];
    float* out = (float*)d_out;

    unsigned short* hb  = (unsigned short*)d_ws;                  // 16M shorts
    unsigned short* Wt  = hb + (size_t)B_ * S_ * DM_;             // 3M shorts
    unsigned short* qkv = Wt + (size_t)3 * DM_ * DM_;             // 48M shorts
    float* kvpart = (float*)(qkv + (size_t)3 * (B_ * S_) * DM_);
    float* kspart = kvpart + (size_t)B_ * H_ * NT_ * D_ * D_;
    float* vspart = kspart + (size_t)B_ * H_ * NT_ * D_;
    float* kvf    = vspart + (size_t)B_ * H_ * NT_ * D_;
    float* ksum   = kvf + (size_t)B_ * H_ * D_ * D_;
    float* vsum   = ksum + (size_t)B_ * H_ * D_;
    float* msum   = vsum + (size_t)B_ * H_ * D_;

    msum_kernel<<<B_, 256, 0, stream>>>(mask, msum);
    convH<<<(B_ * S_ * DM_) / (256 * 8), 256, 0, stream>>>(hidden, hb);
    transposeW<<<dim3(16, 16, 3), 256, 0, stream>>>(Wq, Wk, Wv, Wt);
    gemm_qkv<<<3072, 256, 0, stream>>>(hb, Wt, bq, bk, bv, qkv);
    attnA<<<dim3(NT_, H_, B_), 256, 0, stream>>>(qkv, mask, kvpart, kspart, vspart);
    reduceKV<<<B_ * H_, 256, 0, stream>>>(kvpart, kspart, vspart, kvf, ksum, vsum);
    attnB<<<dim3(S_ / 64, H_, B_), 256, 0, stream>>>(qkv, mask, kvf, ksum, vsum, msum, out);
}